// Round 1
// baseline (7467.495 us; speedup 1.0000x reference)
//
#include <hip/hip_runtime.h>
#include <math.h>

// AKOrN layer, fp32 baseline.
// v0 = normalize_d(x @ W_in)            [B, OUT, D]
// K  = tanh(coupling)                   [OUT, OUT]
// 8x: v = normalize_d(v + (K @_j v) + omega)
//
// B=8192, IN=1024, OUT=1024, D=4. ~620 GFLOP fp32 total.
// Ping-pong: v0 -> d_out, steps alternate d_out <-> ws, step 8 writes d_out.
// ws layout: [0, 4MB) = tanh(coupling); [4MB, 4MB+134MB) = v ping buffer.

#define B_SZ   8192
#define IN_SZ  1024
#define OUT_SZ 1024
#define DSZ    4
#define STEPS  8
#define EPSN   1e-12f

// ---------------------------------------------------------------- tanh(K)
__global__ void tanh_kernel(const float* __restrict__ c,
                            float* __restrict__ K, int n) {
    int i = blockIdx.x * blockDim.x + threadIdx.x;
    if (i < n) K[i] = tanhf(c[i]);
}

// ---------------------------------------------------------------- init GEMM
// vout[b,o,d] = normalize_d( sum_k x[b,k] * W[k,o,d] )
// Tile: 64 o x 64 b x 4 d per block, 256 threads, per-thread 4o x 4b x 4d.
__global__ __launch_bounds__(256) void init_kernel(
    const float* __restrict__ x,    // [B][IN]
    const float* __restrict__ W,    // [IN][OUT][D]
    float* __restrict__ vout)       // [B][OUT][D]
{
    __shared__ __align__(16) float Xt[32][65];    // Xt[kk][b_local]   (scalar reads)
    __shared__ __align__(16) float Wt[64][132];   // Wt[o_local][4*kk+d] (b128 reads)

    const int tid = threadIdx.x;
    const int tx  = tid & 15;            // o lane
    const int ty  = tid >> 4;            // b lane
    const int o0  = blockIdx.x * 64;
    const int b0  = blockIdx.y * 64;

    float4 acc[4][4];
#pragma unroll
    for (int i = 0; i < 4; ++i)
#pragma unroll
        for (int j = 0; j < 4; ++j) acc[i][j] = make_float4(0.f, 0.f, 0.f, 0.f);

    for (int k0 = 0; k0 < IN_SZ; k0 += 32) {
        // stage x tile (transposed into LDS, scalar writes ~2-way conflicts)
#pragma unroll
        for (int q = 0; q < 2; ++q) {
            int f = tid + 256 * q;            // 0..511
            int r = f >> 3, c4 = f & 7;       // r = b_local, c4 = k-float4
            float4 v = *(const float4*)&x[(b0 + r) * IN_SZ + k0 + 4 * c4];
            Xt[4 * c4 + 0][r] = v.x; Xt[4 * c4 + 1][r] = v.y;
            Xt[4 * c4 + 2][r] = v.z; Xt[4 * c4 + 3][r] = v.w;
        }
        // stage W tile ((o,d) contiguous in global -> b128 in/out)
#pragma unroll
        for (int q = 0; q < 8; ++q) {
            int f = tid + 256 * q;            // 0..2047
            int kk = f >> 6, o4 = f & 63;
            *(float4*)&Wt[o4][4 * kk] =
                *(const float4*)&W[((k0 + kk) * OUT_SZ + o0 + o4) * DSZ];
        }
        __syncthreads();

#pragma unroll 8
        for (int kk = 0; kk < 32; ++kk) {
            float  xv[4];
            float4 wv[4];
#pragma unroll
            for (int bb = 0; bb < 4; ++bb) xv[bb] = Xt[kk][ty + 16 * bb];
#pragma unroll
            for (int oo = 0; oo < 4; ++oo)
                wv[oo] = *(const float4*)&Wt[tx + 16 * oo][4 * kk];
#pragma unroll
            for (int oo = 0; oo < 4; ++oo)
#pragma unroll
                for (int bb = 0; bb < 4; ++bb) {
                    acc[oo][bb].x += wv[oo].x * xv[bb];
                    acc[oo][bb].y += wv[oo].y * xv[bb];
                    acc[oo][bb].z += wv[oo].z * xv[bb];
                    acc[oo][bb].w += wv[oo].w * xv[bb];
                }
        }
        __syncthreads();
    }

#pragma unroll
    for (int oo = 0; oo < 4; ++oo) {
        int o = o0 + tx + 16 * oo;
#pragma unroll
        for (int bb = 0; bb < 4; ++bb) {
            int b = b0 + ty + 16 * bb;
            float4 a = acc[oo][bb];
            float n = sqrtf(a.x * a.x + a.y * a.y + a.z * a.z + a.w * a.w);
            float s = 1.0f / fmaxf(n, EPSN);
            a.x *= s; a.y *= s; a.z *= s; a.w *= s;
            *(float4*)&vout[(b * OUT_SZ + o) * DSZ] = a;
        }
    }
}

// ---------------------------------------------------------------- step
// vout[b,i,d] = normalize_d( vin[b,i,d] + sum_j K[i,j]*vin[b,j,d] + omega[i,d] )
// Tile: 64 i x 64 b x 4 d per block, 256 threads, per-thread 4i x 4b x 4d.
__global__ __launch_bounds__(256) void step_kernel(
    const float* __restrict__ vin,   // [B][OUT][D]
    float* __restrict__ vout,        // [B][OUT][D]
    const float* __restrict__ K,     // [OUT][OUT]  (tanh'd)
    const float* __restrict__ omega) // [OUT][D]
{
    __shared__ __align__(16) float Kt[32][65];    // Kt[jj][i_local]
    __shared__ __align__(16) float Vt[64][132];   // Vt[b_local][4*jj+d]

    const int tid = threadIdx.x;
    const int tx  = tid & 15;            // i lane
    const int ty  = tid >> 4;            // b lane
    const int i0  = blockIdx.x * 64;
    const int b0  = blockIdx.y * 64;

    float4 acc[4][4];
#pragma unroll
    for (int i = 0; i < 4; ++i)
#pragma unroll
        for (int j = 0; j < 4; ++j) acc[i][j] = make_float4(0.f, 0.f, 0.f, 0.f);

    for (int j0 = 0; j0 < OUT_SZ; j0 += 32) {
        // stage K tile (transposed)
#pragma unroll
        for (int q = 0; q < 2; ++q) {
            int f = tid + 256 * q;
            int r = f >> 3, c4 = f & 7;       // r = i_local, c4 = j-float4
            float4 v = *(const float4*)&K[(i0 + r) * OUT_SZ + j0 + 4 * c4];
            Kt[4 * c4 + 0][r] = v.x; Kt[4 * c4 + 1][r] = v.y;
            Kt[4 * c4 + 2][r] = v.z; Kt[4 * c4 + 3][r] = v.w;
        }
        // stage v tile ((j,d) contiguous per b)
#pragma unroll
        for (int q = 0; q < 8; ++q) {
            int f = tid + 256 * q;            // 0..2047
            int b = f >> 5, jj = f & 31;
            *(float4*)&Vt[b][4 * jj] =
                *(const float4*)&vin[((b0 + b) * OUT_SZ + j0 + jj) * DSZ];
        }
        __syncthreads();

#pragma unroll 8
        for (int jj = 0; jj < 32; ++jj) {
            float  kv[4];
            float4 vv[4];
#pragma unroll
            for (int ii = 0; ii < 4; ++ii) kv[ii] = Kt[jj][tx + 16 * ii];
#pragma unroll
            for (int bb = 0; bb < 4; ++bb)
                vv[bb] = *(const float4*)&Vt[ty + 16 * bb][4 * jj];
#pragma unroll
            for (int ii = 0; ii < 4; ++ii)
#pragma unroll
                for (int bb = 0; bb < 4; ++bb) {
                    acc[ii][bb].x += kv[ii] * vv[bb].x;
                    acc[ii][bb].y += kv[ii] * vv[bb].y;
                    acc[ii][bb].z += kv[ii] * vv[bb].z;
                    acc[ii][bb].w += kv[ii] * vv[bb].w;
                }
        }
        __syncthreads();
    }

#pragma unroll
    for (int ii = 0; ii < 4; ++ii) {
        int i = i0 + tx + 16 * ii;
        float4 om = *(const float4*)&omega[i * DSZ];
#pragma unroll
        for (int bb = 0; bb < 4; ++bb) {
            int b = b0 + ty + 16 * bb;
            float4 vo = *(const float4*)&vin[(b * OUT_SZ + i) * DSZ];
            float4 a = acc[ii][bb];
            a.x = vo.x + a.x + om.x;       // DT = 1.0
            a.y = vo.y + a.y + om.y;
            a.z = vo.z + a.z + om.z;
            a.w = vo.w + a.w + om.w;
            float n = sqrtf(a.x * a.x + a.y * a.y + a.z * a.z + a.w * a.w);
            float s = 1.0f / fmaxf(n, EPSN);
            a.x *= s; a.y *= s; a.z *= s; a.w *= s;
            *(float4*)&vout[(b * OUT_SZ + i) * DSZ] = a;
        }
    }
}

// ---------------------------------------------------------------- launch
extern "C" void kernel_launch(void* const* d_in, const int* in_sizes, int n_in,
                              void* d_out, int out_size, void* d_ws, size_t ws_size,
                              hipStream_t stream) {
    const float* x        = (const float*)d_in[0];  // [8192,1024]
    const float* W_in     = (const float*)d_in[1];  // [1024,1024,4]
    const float* omega    = (const float*)d_in[2];  // [1024,4]
    const float* coupling = (const float*)d_in[3];  // [1024,1024]
    float* out  = (float*)d_out;                    // [8192,1024,4]

    float* Kbuf = (float*)d_ws;                     // 4 MB
    float* vbuf = Kbuf + (size_t)OUT_SZ * OUT_SZ;   // 134 MB ping buffer

    tanh_kernel<<<(OUT_SZ * OUT_SZ + 255) / 256, 256, 0, stream>>>(
        coupling, Kbuf, OUT_SZ * OUT_SZ);

    init_kernel<<<dim3(OUT_SZ / 64, B_SZ / 64), 256, 0, stream>>>(x, W_in, out);

    for (int s = 0; s < STEPS; ++s) {
        const float* vi = (s & 1) ? vbuf : out;
        float*       vo = (s & 1) ? out  : vbuf;   // s=7 writes d_out
        step_kernel<<<dim3(OUT_SZ / 64, B_SZ / 64), 256, 0, stream>>>(
            vi, vo, Kbuf, omega);
    }
}

// Round 2
// 4455.176 us; speedup vs baseline: 1.6761x; 1.6761x over previous
//
#include <hip/hip_runtime.h>
#include <math.h>

// AKOrN layer — split-bf16 MFMA steps.
//
// v0 = normalize_d(x @ W_in)                      (fp32 VALU GEMM)
// K' = tanh(coupling) + I                         (identity folded in)
// 8x: v = normalize_d(K' v + omega)               (split-bf16 MFMA GEMM)
//
// Precision scheme: K' and v are each split into hi+lo bf16 (residual ~2^-18
// relative). agg = Ah*Bh + Al*Bh + Ah*Bl via mfma_f32_16x16x32_bf16 with fp32
// accumulation -> ~fp32-quality products at 3x bf16-MFMA cost.
//
// State between steps: bf16 planes [d][B][OUT], hi and lo.
//   ws:    Khi(2MB) Klo(2MB) planesA_hi(64MB) planesA_lo(64MB)   = 132 MB
//   d_out: reused as planesB (hi 64MB + lo 64MB = 128MB < 134MB)
// Sequence: init->B, s0:B->A, s1:A->B, ... s6:B->A, s7:A->d_out(fp32).

#define B_SZ   8192
#define IN_SZ  1024
#define OUT_SZ 1024
#define STEPS  8
#define EPSN   1e-12f
#define PLANE  ((size_t)B_SZ * OUT_SZ)   // elements per d-plane

typedef __attribute__((ext_vector_type(8))) short  short8;   // 8 bf16 = 4 VGPR
typedef __attribute__((ext_vector_type(4))) float  f32x4;
typedef __attribute__((ext_vector_type(4))) int    int4v;    // 16B copy unit

__device__ __forceinline__ unsigned short f2bf(float f) {
    union { float f; unsigned u; } v; v.f = f;
    unsigned r = v.u + 0x7FFFu + ((v.u >> 16) & 1u);   // RNE, inputs are tame (no NaN/inf)
    return (unsigned short)(r >> 16);
}
__device__ __forceinline__ float bf2f(unsigned short h) {
    union { unsigned u; float f; } v; v.u = ((unsigned)h) << 16;
    return v.f;
}

// ------------------------------------------------ K' = tanh(c) + I, split
__global__ void tanhsplit_kernel(const float* __restrict__ c,
                                 unsigned short* __restrict__ Khi,
                                 unsigned short* __restrict__ Klo) {
    int idx = blockIdx.x * 256 + threadIdx.x;          // grid exactly OUT*OUT/256
    float val = tanhf(c[idx]) + (((idx >> 10) == (idx & (OUT_SZ - 1))) ? 1.0f : 0.0f);
    unsigned short hi = f2bf(val);
    float r = val - bf2f(hi);
    Khi[idx] = hi;
    Klo[idx] = f2bf(r);
}

// ------------------------------------------------ init GEMM (fp32, as R1)
// vout = normalize_d(x @ W_in), written as split bf16 planes [d][B][OUT].
__global__ __launch_bounds__(256) void init_kernel(
    const float* __restrict__ x,    // [B][IN]
    const float* __restrict__ W,    // [IN][OUT][4]
    unsigned short* __restrict__ Vhi,  // [4][B][OUT]
    unsigned short* __restrict__ Vlo)
{
    __shared__ __align__(16) float Xt[32][65];
    __shared__ __align__(16) float Wt[64][132];

    const int tid = threadIdx.x;
    const int tx  = tid & 15;            // o lane
    const int ty  = tid >> 4;            // b lane
    const int o0  = blockIdx.x * 64;
    const int b0  = blockIdx.y * 64;

    float4 acc[4][4];
#pragma unroll
    for (int i = 0; i < 4; ++i)
#pragma unroll
        for (int j = 0; j < 4; ++j) acc[i][j] = make_float4(0.f, 0.f, 0.f, 0.f);

    for (int k0 = 0; k0 < IN_SZ; k0 += 32) {
#pragma unroll
        for (int q = 0; q < 2; ++q) {
            int f = tid + 256 * q;
            int r = f >> 3, c4 = f & 7;
            float4 v = *(const float4*)&x[(b0 + r) * IN_SZ + k0 + 4 * c4];
            Xt[4 * c4 + 0][r] = v.x; Xt[4 * c4 + 1][r] = v.y;
            Xt[4 * c4 + 2][r] = v.z; Xt[4 * c4 + 3][r] = v.w;
        }
#pragma unroll
        for (int q = 0; q < 8; ++q) {
            int f = tid + 256 * q;
            int kk = f >> 6, o4 = f & 63;
            *(float4*)&Wt[o4][4 * kk] =
                *(const float4*)&W[((k0 + kk) * OUT_SZ + o0 + o4) * 4];
        }
        __syncthreads();

#pragma unroll 8
        for (int kk = 0; kk < 32; ++kk) {
            float  xv[4];
            float4 wv[4];
#pragma unroll
            for (int bb = 0; bb < 4; ++bb) xv[bb] = Xt[kk][ty + 16 * bb];
#pragma unroll
            for (int oo = 0; oo < 4; ++oo)
                wv[oo] = *(const float4*)&Wt[tx + 16 * oo][4 * kk];
#pragma unroll
            for (int oo = 0; oo < 4; ++oo)
#pragma unroll
                for (int bb = 0; bb < 4; ++bb) {
                    acc[oo][bb].x += wv[oo].x * xv[bb];
                    acc[oo][bb].y += wv[oo].y * xv[bb];
                    acc[oo][bb].z += wv[oo].z * xv[bb];
                    acc[oo][bb].w += wv[oo].w * xv[bb];
                }
        }
        __syncthreads();
    }

#pragma unroll
    for (int oo = 0; oo < 4; ++oo) {
        int o = o0 + tx + 16 * oo;
#pragma unroll
        for (int bb = 0; bb < 4; ++bb) {
            int b = b0 + ty + 16 * bb;
            float4 a = acc[oo][bb];
            float n = sqrtf(a.x * a.x + a.y * a.y + a.z * a.z + a.w * a.w);
            float s = 1.0f / fmaxf(n, EPSN);
            float tv[4] = { a.x * s, a.y * s, a.z * s, a.w * s };
#pragma unroll
            for (int d = 0; d < 4; ++d) {
                unsigned short hi = f2bf(tv[d]);
                float r = tv[d] - bf2f(hi);
                size_t idx = (size_t)d * PLANE + (size_t)b * OUT_SZ + o;
                Vhi[idx] = hi;
                Vlo[idx] = f2bf(r);
            }
        }
    }
}

// ------------------------------------------------ step: v' = norm(K' v + w)
// Block: BM=128 i x 32 b x 4 d, 256 threads = 4 waves (wm = wave&1: i-half,
// wn = wave>>1: b-half). Wave tile: 64 i x 16 b x 4 d.
// MFMA 16x16x32 bf16: A lane m=lane&15, k=(lane>>4)*8+j; B lane n=lane&15,
// k=(lane>>4)*8+j; C lane col=lane&15, row=(lane>>4)*4+reg.
// LDS tiles stored fragment-major: slot = (frag*64 + lane)*8 bf16 -> all
// ds_read/ds_write are lane-linear b128 (conflict-free).
__global__ __launch_bounds__(256) void step_mfma_kernel(
    const unsigned short* __restrict__ Vhi,  // [4][B][OUT]
    const unsigned short* __restrict__ Vlo,
    const unsigned short* __restrict__ Khi,  // [OUT][OUT] = tanh + I
    const unsigned short* __restrict__ Klo,
    const float* __restrict__ omega,         // [OUT][4]
    unsigned short* __restrict__ Ohi,        // [4][B][OUT]   (if !final)
    unsigned short* __restrict__ Olo,
    float* __restrict__ out,                 // [B][OUT][4]   (if final)
    int final_step)
{
    __shared__ short Ah[4096], Al[4096], Bh[4096], Bl[4096];  // 8 KB each

    const int tid = threadIdx.x;
    const int ln  = tid & 63;
    const int wv  = tid >> 6;
    const int wm  = wv & 1;
    const int wn  = wv >> 1;
    const int i0  = blockIdx.x * 128;
    const int b0  = blockIdx.y * 32;

    f32x4 acc[4][4];   // [d][m_frag]
#pragma unroll
    for (int d = 0; d < 4; ++d)
#pragma unroll
        for (int mf = 0; mf < 4; ++mf)
            acc[d][mf] = (f32x4){0.f, 0.f, 0.f, 0.f};

    for (int j0 = 0; j0 < OUT_SZ; j0 += 32) {
        __syncthreads();
        // stage A (K' rows i0..i0+128, cols j0..j0+32): 512 x 16B chunks hi+lo
#pragma unroll
        for (int r = 0; r < 2; ++r) {
            int cid = tid + 256 * r;
            int il = cid >> 2, q = cid & 3;
            int slot = ((il >> 4) * 64 + q * 16 + (il & 15)) * 8;
            size_t g = (size_t)(i0 + il) * OUT_SZ + j0 + q * 8;
            *(int4v*)&Ah[slot] = *(const int4v*)&Khi[g];
            *(int4v*)&Al[slot] = *(const int4v*)&Klo[g];
        }
        // stage B (V planes, rows b0..b0+32, cols j0..j0+32, all 4 d)
#pragma unroll
        for (int r = 0; r < 2; ++r) {
            int cid = tid + 256 * r;
            int d = cid >> 7, bl_ = (cid >> 2) & 31, q = cid & 3;
            int slot = ((d * 2 + (bl_ >> 4)) * 64 + q * 16 + (bl_ & 15)) * 8;
            size_t g = (size_t)d * PLANE + (size_t)(b0 + bl_) * OUT_SZ + j0 + q * 8;
            *(int4v*)&Bh[slot] = *(const int4v*)&Vhi[g];
            *(int4v*)&Bl[slot] = *(const int4v*)&Vlo[g];
        }
        __syncthreads();

        short8 ah[4], al[4], bh[4], bl[4];
#pragma unroll
        for (int mf = 0; mf < 4; ++mf) {
            ah[mf] = *(const short8*)&Ah[((wm * 4 + mf) * 64 + ln) * 8];
            al[mf] = *(const short8*)&Al[((wm * 4 + mf) * 64 + ln) * 8];
        }
#pragma unroll
        for (int d = 0; d < 4; ++d) {
            bh[d] = *(const short8*)&Bh[((d * 2 + wn) * 64 + ln) * 8];
            bl[d] = *(const short8*)&Bl[((d * 2 + wn) * 64 + ln) * 8];
        }
#pragma unroll
        for (int d = 0; d < 4; ++d)
#pragma unroll
            for (int mf = 0; mf < 4; ++mf) {
                acc[d][mf] = __builtin_amdgcn_mfma_f32_16x16x32_bf16(ah[mf], bh[d], acc[d][mf], 0, 0, 0);
                acc[d][mf] = __builtin_amdgcn_mfma_f32_16x16x32_bf16(al[mf], bh[d], acc[d][mf], 0, 0, 0);
                acc[d][mf] = __builtin_amdgcn_mfma_f32_16x16x32_bf16(ah[mf], bl[d], acc[d][mf], 0, 0, 0);
            }
    }

    // epilogue: normalize over d, write planes (or fp32 out on final step)
    const int b = b0 + wn * 16 + (ln & 15);
#pragma unroll
    for (int mf = 0; mf < 4; ++mf) {
#pragma unroll
        for (int reg = 0; reg < 4; ++reg) {
            int i = i0 + wm * 64 + mf * 16 + (ln >> 4) * 4 + reg;
            const f32x4 om = *(const f32x4*)&omega[i * 4];
            float tv[4];
#pragma unroll
            for (int d = 0; d < 4; ++d) tv[d] = acc[d][mf][reg] + om[d];
            float n = sqrtf(tv[0] * tv[0] + tv[1] * tv[1] + tv[2] * tv[2] + tv[3] * tv[3]);
            float s = 1.0f / fmaxf(n, EPSN);
            if (final_step) {
                f32x4 rr = { tv[0] * s, tv[1] * s, tv[2] * s, tv[3] * s };
                *(f32x4*)&out[((size_t)b * OUT_SZ + i) * 4] = rr;
            } else {
#pragma unroll
                for (int d = 0; d < 4; ++d) {
                    float val = tv[d] * s;
                    unsigned short hi = f2bf(val);
                    float r = val - bf2f(hi);
                    size_t idx = (size_t)d * PLANE + (size_t)b * OUT_SZ + i;
                    Ohi[idx] = hi;
                    Olo[idx] = f2bf(r);
                }
            }
        }
    }
}

// ------------------------------------------------ launch
extern "C" void kernel_launch(void* const* d_in, const int* in_sizes, int n_in,
                              void* d_out, int out_size, void* d_ws, size_t ws_size,
                              hipStream_t stream) {
    const float* x        = (const float*)d_in[0];  // [8192,1024]
    const float* W_in     = (const float*)d_in[1];  // [1024,1024,4]
    const float* omega    = (const float*)d_in[2];  // [1024,4]
    const float* coupling = (const float*)d_in[3];  // [1024,1024]
    float* out = (float*)d_out;

    unsigned short* Khi = (unsigned short*)d_ws;                 // 2 MB
    unsigned short* Klo = Khi + (size_t)OUT_SZ * OUT_SZ;         // 2 MB
    unsigned short* Ahi = Klo + (size_t)OUT_SZ * OUT_SZ;         // 64 MB
    unsigned short* Alo = Ahi + 4 * PLANE;                       // 64 MB
    unsigned short* Bhi = (unsigned short*)d_out;                // 64 MB (aliases out)
    unsigned short* Blo = Bhi + 4 * PLANE;                       // 64 MB (aliases out)

    tanhsplit_kernel<<<(OUT_SZ * OUT_SZ) / 256, 256, 0, stream>>>(coupling, Khi, Klo);

    // v0 -> planes B (d_out region)
    init_kernel<<<dim3(OUT_SZ / 64, B_SZ / 64), 256, 0, stream>>>(x, W_in, Bhi, Blo);

    // s even: B->A, s odd: A->B; s=7 (odd, reads A) writes fp32 d_out
    for (int s = 0; s < STEPS; ++s) {
        const unsigned short* Shi = (s & 1) ? Ahi : Bhi;
        const unsigned short* Slo = (s & 1) ? Alo : Blo;
        unsigned short*       Dhi = (s & 1) ? Bhi : Ahi;
        unsigned short*       Dlo = (s & 1) ? Blo : Alo;
        int fin = (s == STEPS - 1);
        step_mfma_kernel<<<dim3(OUT_SZ / 128, B_SZ / 32), 256, 0, stream>>>(
            Shi, Slo, Khi, Klo, omega, Dhi, Dlo, out, fin);
    }
}

// Round 3
// 2807.680 us; speedup vs baseline: 2.6597x; 1.5868x over previous
//
#include <hip/hip_runtime.h>
#include <math.h>

// AKOrN layer — split-bf16 MFMA for init AND steps, DMA staging, swapped
// operand roles (A = data, B = stationary matrix) so MFMA C-columns are the
// oscillator index -> lane-contiguous epilogue stores.
//
//   v0 = normalize_d(x @ W_in)            (split-bf16 MFMA)
//   K' = tanh(coupling) + I
//   8x: v = normalize_d(K' v + omega)     (split-bf16 MFMA)
//
// Split scheme: operands stored as bf16 hi+lo (residual ~2^-18 rel);
// P = Ah*Bh + Al*Bh + Ah*Bl into fp32 accumulators (3 MFMAs/product).
//
// v planes: [d][B][osc] bf16, hi array then lo array contiguous.
//   ws:    Khi(2M) Klo(2M) | Aplanes hi(67M) lo(67M)          = 138 MB
//   d_out: Bplanes hi+lo (134 MB)
//   prep scratch (Xhi/Xlo/Wthi/Wtlo, 50 MB) aliases the A region (consumed
//   by init before step 0 overwrites it).
// init->B, s0:B->A, s1:A->B, ..., s7:A->d_out(fp32).

#define B_SZ   8192
#define OUT_SZ 1024
#define STEPS  8
#define PLANE  ((size_t)B_SZ * OUT_SZ)
#define WPLANE ((size_t)OUT_SZ * OUT_SZ)

typedef __attribute__((ext_vector_type(8))) short  short8;
typedef __attribute__((ext_vector_type(4))) float  f32x4;
typedef unsigned short us;

__device__ __forceinline__ us f2bf(float f) {
    union { float f; unsigned u; } v; v.f = f;
    unsigned r = v.u + 0x7FFFu + ((v.u >> 16) & 1u);
    return (us)(r >> 16);
}
__device__ __forceinline__ float bf2f(us h) {
    union { unsigned u; float f; } v; v.u = ((unsigned)h) << 16;
    return v.f;
}
// async global->LDS, 16B per lane, dest = uniform base + lane*16
__device__ __forceinline__ void dma16(const void* g, void* l) {
    __builtin_amdgcn_global_load_lds(
        (const __attribute__((address_space(1))) void*)g,
        (__attribute__((address_space(3))) void*)l, 16, 0, 0);
}
__device__ __forceinline__ float rnorm4(float a, float b, float c, float d) {
    float n2 = a * a + b * b + c * c + d * d;
    float s = rsqrtf(fmaxf(n2, 1e-24f));
    return s * (1.5f - 0.5f * n2 * s * s);   // 1 NR step -> fp32 accuracy
}

// ------------------------------------------------ prep: K' = tanh(c)+I, split
__global__ void tanhsplit_kernel(const float* __restrict__ c,
                                 us* __restrict__ Khi, us* __restrict__ Klo) {
    int idx = blockIdx.x * 256 + threadIdx.x;
    float val = tanhf(c[idx]) + (((idx >> 10) == (idx & (OUT_SZ - 1))) ? 1.0f : 0.0f);
    us hi = f2bf(val);
    Khi[idx] = hi;
    Klo[idx] = f2bf(val - bf2f(hi));
}

// ------------------------------------------------ prep: split x -> bf16 hi/lo
__global__ void xsplit_kernel(const float* __restrict__ x,
                              us* __restrict__ Xhi, us* __restrict__ Xlo) {
    int idx = (blockIdx.x * 256 + threadIdx.x) * 4;
    float4 v = *(const float4*)&x[idx];
    float p[4] = { v.x, v.y, v.z, v.w };
    unsigned h01, h23, l01, l23;
    us h[4], l[4];
#pragma unroll
    for (int t = 0; t < 4; ++t) {
        h[t] = f2bf(p[t]);
        l[t] = f2bf(p[t] - bf2f(h[t]));
    }
    h01 = (unsigned)h[0] | ((unsigned)h[1] << 16);
    h23 = (unsigned)h[2] | ((unsigned)h[3] << 16);
    l01 = (unsigned)l[0] | ((unsigned)l[1] << 16);
    l23 = (unsigned)l[2] | ((unsigned)l[3] << 16);
    ((unsigned*)Xhi)[idx / 2]     = h01;
    ((unsigned*)Xhi)[idx / 2 + 1] = h23;
    ((unsigned*)Xlo)[idx / 2]     = l01;
    ((unsigned*)Xlo)[idx / 2 + 1] = l23;
}

// ------------------------------------------------ prep: W [k][o][d] -> Wt [d][o][k] split
__global__ void wprep_kernel(const float* __restrict__ W,
                             us* __restrict__ Wthi, us* __restrict__ Wtlo) {
    int idx = blockIdx.x * 256 + threadIdx.x;        // 262144 total
    int d  = idx & 3;
    int o  = (idx >> 2) & (OUT_SZ - 1);
    int kc = idx >> 12;                              // 0..63, 16 k each
    us h[16], l[16];
#pragma unroll
    for (int t = 0; t < 16; ++t) {
        float v = W[((size_t)(kc * 16 + t) * OUT_SZ + o) * 4 + d];
        h[t] = f2bf(v);
        l[t] = f2bf(v - bf2f(h[t]));
    }
    size_t base = (size_t)d * WPLANE + (size_t)o * OUT_SZ + kc * 16;
#pragma unroll
    for (int t = 0; t < 16; ++t) { Wthi[base + t] = h[t]; Wtlo[base + t] = l[t]; }
}

// ------------------------------------------------ step: v' = norm(K' v + w)
// A = v (m=b), B = K' (n=i).  Block 32 b x 128 i, 4 waves:
// wm = wv&1 -> 16-b half, wn = wv>>1 -> 64-i half (nf=0..3).
// LDS frag slots: 512 shorts (64 lanes x 16B), lane-linear (DMA-compatible).
__global__ __launch_bounds__(256, 3) void step_mfma_kernel(
    const us* __restrict__ Vhi, const us* __restrict__ Vlo,
    const us* __restrict__ Khi, const us* __restrict__ Klo,
    const float* __restrict__ omega,
    us* __restrict__ Ohi, us* __restrict__ Olo,
    float* __restrict__ out, int final_step)
{
    __shared__ short As[8192];   // v tile:  frag (d*2+bh)*2+hl
    __shared__ short Bs[8192];   // K' tile: frag ib*2+hl

    const int tid = threadIdx.x;
    const int ln = tid & 63, wv = tid >> 6;
    const int wm = wv & 1, wn = wv >> 1;
    const int i0 = blockIdx.x * 128;
    const int b0 = blockIdx.y * 32;

    // 8 DMA frags per wave: waves 0,1 -> A (16 frags), waves 2,3 -> B (16 frags)
    const us* gsrc[8];
    short*    ldst[8];
    if (wv < 2) {
        int t = 0;
#pragma unroll
        for (int dq = 0; dq < 2; ++dq)
#pragma unroll
            for (int bh = 0; bh < 2; ++bh)
#pragma unroll
                for (int hl = 0; hl < 2; ++hl) {
                    int d = wv * 2 + dq;
                    int b = b0 + bh * 16 + (ln & 15);
                    const us* base = hl ? Vlo : Vhi;
                    gsrc[t] = base + (size_t)d * PLANE + (size_t)b * OUT_SZ + (ln >> 4) * 8;
                    ldst[t] = &As[((d * 2 + bh) * 2 + hl) * 512];
                    ++t;
                }
    } else {
        int t = 0;
#pragma unroll
        for (int iq = 0; iq < 4; ++iq)
#pragma unroll
            for (int hl = 0; hl < 2; ++hl) {
                int ib = (wv - 2) * 4 + iq;
                int i = i0 + ib * 16 + (ln & 15);
                const us* base = hl ? Klo : Khi;
                gsrc[t] = base + (size_t)i * OUT_SZ + (ln >> 4) * 8;
                ldst[t] = &Bs[(ib * 2 + hl) * 512];
                ++t;
            }
    }

    f32x4 acc[4][4];   // [d][nf]
#pragma unroll
    for (int d = 0; d < 4; ++d)
#pragma unroll
        for (int nf = 0; nf < 4; ++nf) acc[d][nf] = (f32x4){0.f, 0.f, 0.f, 0.f};

    for (int j0 = 0; j0 < OUT_SZ; j0 += 32) {
        __syncthreads();
#pragma unroll
        for (int t = 0; t < 8; ++t) {
            dma16(gsrc[t], ldst[t]);
            gsrc[t] += 32;
        }
        __syncthreads();

        short8 a[4][2], b[4][2];
#pragma unroll
        for (int d = 0; d < 4; ++d)
#pragma unroll
            for (int hl = 0; hl < 2; ++hl)
                a[d][hl] = *(const short8*)&As[(((d * 2 + wm) * 2 + hl)) * 512 + ln * 8];
#pragma unroll
        for (int nf = 0; nf < 4; ++nf)
#pragma unroll
            for (int hl = 0; hl < 2; ++hl)
                b[nf][hl] = *(const short8*)&Bs[((wn * 4 + nf) * 2 + hl) * 512 + ln * 8];

#pragma unroll
        for (int d = 0; d < 4; ++d)
#pragma unroll
            for (int nf = 0; nf < 4; ++nf) {
                acc[d][nf] = __builtin_amdgcn_mfma_f32_16x16x32_bf16(a[d][0], b[nf][0], acc[d][nf], 0, 0, 0);
                acc[d][nf] = __builtin_amdgcn_mfma_f32_16x16x32_bf16(a[d][1], b[nf][0], acc[d][nf], 0, 0, 0);
                acc[d][nf] = __builtin_amdgcn_mfma_f32_16x16x32_bf16(a[d][0], b[nf][1], acc[d][nf], 0, 0, 0);
            }
    }

    // epilogue: C row = b, col = i (lane-contiguous stores)
#pragma unroll
    for (int nf = 0; nf < 4; ++nf) {
        const int i = i0 + wn * 64 + nf * 16 + (ln & 15);
        const f32x4 om = *(const f32x4*)&omega[i * 4];
#pragma unroll
        for (int reg = 0; reg < 4; ++reg) {
            const int b = b0 + wm * 16 + (ln >> 4) * 4 + reg;
            float tv[4];
#pragma unroll
            for (int d = 0; d < 4; ++d) tv[d] = acc[d][nf][reg] + om[d];
            float s = rnorm4(tv[0], tv[1], tv[2], tv[3]);
            if (final_step) {
                f32x4 rr = { tv[0] * s, tv[1] * s, tv[2] * s, tv[3] * s };
                *(f32x4*)&out[((size_t)b * OUT_SZ + i) * 4] = rr;
            } else {
#pragma unroll
                for (int d = 0; d < 4; ++d) {
                    float val = tv[d] * s;
                    us hi = f2bf(val);
                    size_t idx = (size_t)d * PLANE + (size_t)b * OUT_SZ + i;
                    Ohi[idx] = hi;
                    Olo[idx] = f2bf(val - bf2f(hi));
                }
            }
        }
    }
}

// ------------------------------------------------ init: v0 = norm(x @ W)
// A = x (m=b, d-independent), B = Wt planes (n=o, per d).
// Block 128 b x 32 o, 4 waves: wm -> 64-b half (mf=0..3), wn -> 16-o half.
__global__ __launch_bounds__(256, 3) void init_mfma_kernel(
    const us* __restrict__ Xhi, const us* __restrict__ Xlo,
    const us* __restrict__ Wthi, const us* __restrict__ Wtlo,
    us* __restrict__ Ohi, us* __restrict__ Olo)
{
    __shared__ short As[8192];   // x tile:  frag bf*2+hl  (bf=0..7)
    __shared__ short Bs[8192];   // Wt tile: frag (d*2+oh)*2+hl

    const int tid = threadIdx.x;
    const int ln = tid & 63, wv = tid >> 6;
    const int wm = wv & 1, wn = wv >> 1;
    const int b0 = blockIdx.x * 128;
    const int o0 = blockIdx.y * 32;

    const us* gsrc[8];
    short*    ldst[8];
    if (wv < 2) {
        int t = 0;
#pragma unroll
        for (int bq = 0; bq < 4; ++bq)
#pragma unroll
            for (int hl = 0; hl < 2; ++hl) {
                int bf = wv * 4 + bq;
                int b = b0 + bf * 16 + (ln & 15);
                const us* base = hl ? Xlo : Xhi;
                gsrc[t] = base + (size_t)b * 1024 + (ln >> 4) * 8;
                ldst[t] = &As[(bf * 2 + hl) * 512];
                ++t;
            }
    } else {
        int t = 0;
#pragma unroll
        for (int dq = 0; dq < 2; ++dq)
#pragma unroll
            for (int oh = 0; oh < 2; ++oh)
#pragma unroll
                for (int hl = 0; hl < 2; ++hl) {
                    int d = (wv - 2) * 2 + dq;
                    int o = o0 + oh * 16 + (ln & 15);
                    const us* base = hl ? Wtlo : Wthi;
                    gsrc[t] = base + (size_t)d * WPLANE + (size_t)o * OUT_SZ + (ln >> 4) * 8;
                    ldst[t] = &Bs[((d * 2 + oh) * 2 + hl) * 512];
                    ++t;
                }
    }

    f32x4 acc[4][4];   // [d][mf]
#pragma unroll
    for (int d = 0; d < 4; ++d)
#pragma unroll
        for (int mf = 0; mf < 4; ++mf) acc[d][mf] = (f32x4){0.f, 0.f, 0.f, 0.f};

    for (int k0 = 0; k0 < 1024; k0 += 32) {
        __syncthreads();
#pragma unroll
        for (int t = 0; t < 8; ++t) {
            dma16(gsrc[t], ldst[t]);
            gsrc[t] += 32;
        }
        __syncthreads();

        short8 a[4][2], b[4][2];
#pragma unroll
        for (int mf = 0; mf < 4; ++mf)
#pragma unroll
            for (int hl = 0; hl < 2; ++hl)
                a[mf][hl] = *(const short8*)&As[((wm * 4 + mf) * 2 + hl) * 512 + ln * 8];
#pragma unroll
        for (int d = 0; d < 4; ++d)
#pragma unroll
            for (int hl = 0; hl < 2; ++hl)
                b[d][hl] = *(const short8*)&Bs[((d * 2 + wn) * 2 + hl) * 512 + ln * 8];

#pragma unroll
        for (int d = 0; d < 4; ++d)
#pragma unroll
            for (int mf = 0; mf < 4; ++mf) {
                acc[d][mf] = __builtin_amdgcn_mfma_f32_16x16x32_bf16(a[mf][0], b[d][0], acc[d][mf], 0, 0, 0);
                acc[d][mf] = __builtin_amdgcn_mfma_f32_16x16x32_bf16(a[mf][1], b[d][0], acc[d][mf], 0, 0, 0);
                acc[d][mf] = __builtin_amdgcn_mfma_f32_16x16x32_bf16(a[mf][0], b[d][1], acc[d][mf], 0, 0, 0);
            }
    }

    const int o = o0 + wn * 16 + (ln & 15);
#pragma unroll
    for (int mf = 0; mf < 4; ++mf)
#pragma unroll
        for (int reg = 0; reg < 4; ++reg) {
            const int b = b0 + wm * 64 + mf * 16 + (ln >> 4) * 4 + reg;
            float tv[4];
#pragma unroll
            for (int d = 0; d < 4; ++d) tv[d] = acc[d][mf][reg];
            float s = rnorm4(tv[0], tv[1], tv[2], tv[3]);
#pragma unroll
            for (int d = 0; d < 4; ++d) {
                float val = tv[d] * s;
                us hi = f2bf(val);
                size_t idx = (size_t)d * PLANE + (size_t)b * OUT_SZ + o;
                Ohi[idx] = hi;
                Olo[idx] = f2bf(val - bf2f(hi));
            }
        }
}

// ------------------------------------------------ launch
extern "C" void kernel_launch(void* const* d_in, const int* in_sizes, int n_in,
                              void* d_out, int out_size, void* d_ws, size_t ws_size,
                              hipStream_t stream) {
    const float* x        = (const float*)d_in[0];
    const float* W_in     = (const float*)d_in[1];
    const float* omega    = (const float*)d_in[2];
    const float* coupling = (const float*)d_in[3];
    float* out = (float*)d_out;

    us* Khi = (us*)d_ws;
    us* Klo = Khi + WPLANE;
    us* Ahi = Klo + WPLANE;          // ping planes (134 MB hi+lo)
    us* Alo = Ahi + 4 * PLANE;
    us* Bhi = (us*)d_out;            // pong planes alias d_out
    us* Blo = Bhi + 4 * PLANE;

    // prep scratch aliased into A region (init consumes before s0 overwrites)
    us* Xhi  = Ahi;
    us* Xlo  = Xhi + (size_t)B_SZ * 1024;
    us* Wthi = Xlo + (size_t)B_SZ * 1024;
    us* Wtlo = Wthi + 4 * WPLANE;

    tanhsplit_kernel<<<(OUT_SZ * OUT_SZ) / 256, 256, 0, stream>>>(coupling, Khi, Klo);
    xsplit_kernel<<<(B_SZ * 1024) / 1024, 256, 0, stream>>>(x, Xhi, Xlo);
    wprep_kernel<<<(4 * OUT_SZ * 64) / 256, 256, 0, stream>>>(W_in, Wthi, Wtlo);

    init_mfma_kernel<<<dim3(B_SZ / 128, OUT_SZ / 32), 256, 0, stream>>>(
        Xhi, Xlo, Wthi, Wtlo, Bhi, Blo);

    for (int s = 0; s < STEPS; ++s) {
        const us* Shi = (s & 1) ? Ahi : Bhi;
        const us* Slo = (s & 1) ? Alo : Blo;
        us*       Dhi = (s & 1) ? Bhi : Ahi;
        us*       Dlo = (s & 1) ? Blo : Alo;
        int fin = (s == STEPS - 1);
        step_mfma_kernel<<<dim3(OUT_SZ / 128, B_SZ / 32), 256, 0, stream>>>(
            Shi, Slo, Khi, Klo, omega, Dhi, Dlo, out, fin);
    }
}